// Round 14
// baseline (45.181 us; speedup 1.0000x reference)
//
#include <hip/hip_runtime.h>

// NIoULoss_pixel: B=8, N=8, H=W=512. One-pass fused reduction.
// R14: body = R11 EXACTLY (best: 38.6us; R13's deeper pipeline and R10's
// higher occupancy both ~= it => body is at its ~5.2-6 TB/s service ceiling).
// Change: collapse the serial tail. niou_reduce(320 blk)+niou_final(1 blk)
// (2 launches + gaps ~5us) -> ONE niou_tail kernel: 64 blocks, block bn
// reduces its 5x512 partials -> term_bn; last block (device ticket) atomic-
// loads the 64 terms and writes out[0]. Only contended atomic = ticket
// (64 RMW total - harmless; R12's 512/line disaster respected).

constexpr int Bc  = 8;
constexpr int Nc  = 8;
constexpr int HWc = 512 * 512;
constexpr int BPI = 512;              // blocks per image (512 px per block)
constexpr float EPSc = 1e-6f;

__device__ __forceinline__ float2 gload_f2(const float* a) {
    float2 r;
    asm volatile("global_load_dwordx2 %0, %1, off" : "=v"(r) : "v"(a) : "memory");
    return r;
}
__device__ __forceinline__ int4 gload_i4(const int* a) {
    int4 r;
    asm volatile("global_load_dwordx4 %0, %1, off" : "=v"(r) : "v"(a) : "memory");
    return r;
}
#define WAITV(n_) do {                                                   \
        asm volatile("s_waitcnt vmcnt(" #n_ ")" ::: "memory");           \
        __builtin_amdgcn_sched_barrier(0);                               \
    } while (0)

__device__ __forceinline__ float wave_reduce(float v) {
#pragma unroll
    for (int off = 32; off; off >>= 1) v += __shfl_xor(v, off, 64);
    return v;
}

// 4096 blocks, 256 threads, 512 pixels/block.  (R11 body, unchanged)
template<bool USE_PART>
__global__ __launch_bounds__(256, 4) void niou_partial(
    const float* __restrict__ pd, const float* __restrict__ gt,
    const int* __restrict__ pmask, const int* __restrict__ gmask,
    float* __restrict__ outp /* USE_PART ? part[320][BPI] : ws atomic [320][16] */)
{
    __shared__ float dnL[512], poL[512], goL[512];   // unpadded: b64 W / b128 R

    const int tid  = threadIdx.x;
    const int b    = blockIdx.x >> 9;
    const int blk  = blockIdx.x & 511;
    const int base = blk * 512;

    // ---- issue 8 rgbo dwordx2 loads (oldest in queue) ----
    const float* pdB = pd + (size_t)b * 4 * HWc + base + 2 * tid;
    const float* gtB = gt + (size_t)b * 4 * HWc + base + 2 * tid;
    float2 pr[4], gr[4];
#pragma unroll
    for (int c = 0; c < 4; ++c) pr[c] = gload_f2(pdB + (size_t)c * HWc);
#pragma unroll
    for (int c = 0; c < 4; ++c) gr[c] = gload_f2(gtB + (size_t)c * HWc);

    // ---- issue 8 mask int4 loads: planes 2g,2g+1, quads q and q+64 ----
    const int g = tid >> 6, q = tid & 63;
    int4 pmv[2][2], gmv[2][2];   // [plane pp][quad qq]
#pragma unroll
    for (int pp = 0; pp < 2; ++pp) {
        const size_t pl = (size_t)(b * Nc + 2 * g + pp) * HWc + base + 4 * q;
#pragma unroll
        for (int qq = 0; qq < 2; ++qq) {
            pmv[pp][qq] = gload_i4(pmask + pl + 256 * qq);
            gmv[pp][qq] = gload_i4(gmask + pl + 256 * qq);
        }
    }

    // ---- rgbo done (8 oldest); 8 mask loads still in flight ----
    WAITV(8);
    {
        const float dx0 = pr[0].x - gr[0].x, dy0 = pr[1].x - gr[1].x, dz0 = pr[2].x - gr[2].x;
        const float dx1 = pr[0].y - gr[0].y, dy1 = pr[1].y - gr[1].y, dz1 = pr[2].y - gr[2].y;
        float2 d2, p2, g2;
        d2.x = sqrtf(dx0*dx0 + dy0*dy0 + dz0*dz0);
        d2.y = sqrtf(dx1*dx1 + dy1*dy1 + dz1*dz1);
        p2.x = rintf(pr[3].x); p2.y = rintf(pr[3].y);
        g2.x = rintf(gr[3].x); g2.y = rintf(gr[3].y);
        *reinterpret_cast<float2*>(&dnL[2 * tid]) = d2;
        *reinterpret_cast<float2*>(&poL[2 * tid]) = p2;
        *reinterpret_cast<float2*>(&goL[2 * tid]) = g2;
    }
    __syncthreads();

    // ---- LDS pixel quantities for this thread's two quads ----
    float4 dnq[2], poq[2], goq[2];
#pragma unroll
    for (int qq = 0; qq < 2; ++qq) {
        const int li = 256 * qq + 4 * q;
        dnq[qq] = *reinterpret_cast<const float4*>(&dnL[li]);
        poq[qq] = *reinterpret_cast<const float4*>(&poL[li]);
        goq[qq] = *reinterpret_cast<const float4*>(&goL[li]);
    }

    // acc[pp]: {sim_sum, inter, gt_sum, s_sum}; count via ballot
    float acc[2][4];
    int   wcnt[2];
#pragma unroll
    for (int pp = 0; pp < 2; ++pp) {
        wcnt[pp] = 0;
#pragma unroll
        for (int k = 0; k < 4; ++k) acc[pp][k] = 0.f;
    }

    // ---- counted drain: pp=0 ready at vmcnt(4), pp=1 at vmcnt(0) ----
#pragma unroll
    for (int pp = 0; pp < 2; ++pp) {
        if (pp == 0) WAITV(4); else WAITV(0);
#pragma unroll
        for (int qq = 0; qq < 2; ++qq) {
            const int pmx[4] = {pmv[pp][qq].x, pmv[pp][qq].y, pmv[pp][qq].z, pmv[pp][qq].w};
            const int gmx[4] = {gmv[pp][qq].x, gmv[pp][qq].y, gmv[pp][qq].z, gmv[pp][qq].w};
            const float dnj[4] = {dnq[qq].x, dnq[qq].y, dnq[qq].z, dnq[qq].w};
            const float poj[4] = {poq[qq].x, poq[qq].y, poq[qq].z, poq[qq].w};
            const float goj[4] = {goq[qq].x, goq[qq].y, goq[qq].z, goq[qq].w};
#pragma unroll
            for (int j = 0; j < 4; ++j) {
                const bool P = pmx[j] != 0;
                const bool G = gmx[j] != 0;
                wcnt[pp] += __popcll(__ballot(P));
                const float s = P ? poj[j] : 0.f;
                acc[pp][0] += P ? dnj[j] : 0.f;
                acc[pp][1] += G ? s      : 0.f;   // inter = (P&&G)?po:0
                acc[pp][2] += G ? goj[j] : 0.f;
                acc[pp][3] += s;                  // xor = s_sum - inter (tail)
            }
        }
    }

    // ---- wave-level reduction; lane0 stores 10 partials (no atomics) ----
    const int lane = tid & 63;
#pragma unroll
    for (int pp = 0; pp < 2; ++pp) {
        const float s0 = wave_reduce(acc[pp][0]);
        const float s1 = wave_reduce(acc[pp][1]);
        const float s2 = wave_reduce(acc[pp][2]);
        const float s3 = wave_reduce(acc[pp][3]);
        if (lane == 0) {
            const int n = 2 * g + pp;
            if (USE_PART) {
                float* dst = outp + (size_t)(b * 40 + n * 5) * BPI + blk;
                dst[0 * BPI] = s0;
                dst[1 * BPI] = (float)wcnt[pp];
                dst[2 * BPI] = s1;
                dst[3 * BPI] = s2;
                dst[4 * BPI] = s3;
            } else {   // fallback: 20KB atomic layout (PAD=16)
                float* wsn = outp + (size_t)(b * 40 + n * 5) * 16;
                atomicAdd(&wsn[0 * 16], s0);
                atomicAdd(&wsn[1 * 16], (float)wcnt[pp]);
                atomicAdd(&wsn[2 * 16], s1);
                atomicAdd(&wsn[3 * 16], s2);
                atomicAdd(&wsn[4 * 16], s3);
            }
        }
    }
}

// 64 blocks x 256 threads: block bn reduces its 5 x BPI partials -> term[bn];
// last block to finish (device ticket) sums the 64 terms -> out[0].
__global__ __launch_bounds__(256) void niou_tail(
    const float* __restrict__ part, float* __restrict__ sums,
    unsigned int* __restrict__ ticket, float* __restrict__ out)
{
    const int bn  = blockIdx.x;      // 0..63 == b*8+n
    const int tid = threadIdx.x;

    float loc[5];
#pragma unroll
    for (int s = 0; s < 5; ++s) {
        const float* row = part + ((size_t)bn * 5 + s) * BPI;
        loc[s] = row[tid] + row[tid + 256];
        loc[s] = wave_reduce(loc[s]);
    }

    __shared__ float red[4][5];
    __shared__ bool  last;
    if ((tid & 63) == 0) {
#pragma unroll
        for (int s = 0; s < 5; ++s) red[tid >> 6][s] = loc[s];
    }
    __syncthreads();

    if (tid == 0) {
        const float sim   = red[0][0] + red[1][0] + red[2][0] + red[3][0];
        const float cnt   = red[0][1] + red[1][1] + red[2][1] + red[3][1];
        const float inter = red[0][2] + red[1][2] + red[2][2] + red[3][2];
        const float gts   = red[0][3] + red[1][3] + red[2][3] + red[3][3];
        const float ssum  = red[0][4] + red[1][4] + red[2][4] + red[3][4];
        const float xo    = ssum - inter;            // pd_xor_sum
        const float punish = sim / (cnt + EPSc);
        const float iou    = inter / (gts + xo + EPSc);
        sums[bn] = 1.0f - iou + punish;
        __threadfence();                              // publish before ticket
        last = (atomicAdd(ticket, 1u) == 63u);
    }
    __syncthreads();

    if (last && tid < 64) {
        float term = __hip_atomic_load(&sums[tid], __ATOMIC_RELAXED,
                                       __HIP_MEMORY_SCOPE_AGENT);
        term = wave_reduce(term);
        if (tid == 0) out[0] = term * (1.0f / 64.0f);
    }
}

__global__ __launch_bounds__(64) void niou_final_fb(
    const float* __restrict__ w0, float* __restrict__ out)
{
    const int t = threadIdx.x;   // 0..63 == b*8+n
    const float* w = w0 + (size_t)t * 5 * 16;
    const float sim   = w[0 * 16];
    const float cnt   = w[1 * 16];
    const float inter = w[2 * 16];
    const float gts   = w[3 * 16];
    const float ssum  = w[4 * 16];
    const float xo    = ssum - inter;
    const float punish = sim / (cnt + EPSc);
    const float iou    = inter / (gts + xo + EPSc);
    float term = 1.0f - iou + punish;
#pragma unroll
    for (int off = 32; off; off >>= 1) term += __shfl_xor(term, off, 64);
    if (t == 0) out[0] = term * (1.0f / 64.0f);
}

extern "C" void kernel_launch(void* const* d_in, const int* in_sizes, int n_in,
                              void* d_out, int out_size, void* d_ws, size_t ws_size,
                              hipStream_t stream) {
    const float* pd_rgbo = (const float*)d_in[0];
    const float* gt_rgbo = (const float*)d_in[1];
    const int*   pd_mask = (const int*)d_in[2];
    const int*   gt_mask = (const int*)d_in[3];
    float* out = (float*)d_out;
    float* ws  = (float*)d_ws;

    const size_t partN = (size_t)320 * BPI;                     // floats
    const size_t need  = (partN + 64 + 1) * sizeof(float);
    if (ws_size >= need) {
        float* part = ws;
        float* sums = ws + partN;
        unsigned int* ticket = (unsigned int*)(ws + partN + 64);
        hipMemsetAsync(ticket, 0, sizeof(unsigned int), stream);
        niou_partial<true><<<Bc * BPI, 256, 0, stream>>>(pd_rgbo, gt_rgbo,
                                                         pd_mask, gt_mask, part);
        niou_tail<<<64, 256, 0, stream>>>(part, sums, ticket, out);
    } else {
        hipMemsetAsync(ws, 0, 320 * 16 * sizeof(float), stream);
        niou_partial<false><<<Bc * BPI, 256, 0, stream>>>(pd_rgbo, gt_rgbo,
                                                          pd_mask, gt_mask, ws);
        niou_final_fb<<<1, 64, 0, stream>>>(ws, out);
    }
}

// Round 15
// 38.781 us; speedup vs baseline: 1.1650x; 1.1650x over previous
//
#include <hip/hip_runtime.h>

// NIoULoss_pixel: B=8, N=8, H=W=512. One-pass fused reduction.
// R15: body = R11 EXACTLY (38.6us best; MSHR-capacity-bound at ~6.0 TB/s
// aggregate = ~95% of practical ceiling). Tail minimized: NO memset node
// (R14's 4-byte hipMemsetAsync was a full graph dispatch) — niou_partial
// block 0 zeroes accum+ticket at entry (stream-ordered, race-free); ONE
// niou_tail64 kernel: block bn reduces 5x512 partials -> term_bn ->
// atomicAdd(accum) (64 RMW, harmless); 64th ticket holder writes out.
// 2 launches total vs R11's 3.

constexpr int Bc  = 8;
constexpr int Nc  = 8;
constexpr int HWc = 512 * 512;
constexpr int BPI = 512;              // blocks per image (512 px per block)
constexpr int PARTN = 320 * BPI;      // floats of partials
constexpr float EPSc = 1e-6f;

__device__ __forceinline__ float2 gload_f2(const float* a) {
    float2 r;
    asm volatile("global_load_dwordx2 %0, %1, off" : "=v"(r) : "v"(a) : "memory");
    return r;
}
__device__ __forceinline__ int4 gload_i4(const int* a) {
    int4 r;
    asm volatile("global_load_dwordx4 %0, %1, off" : "=v"(r) : "v"(a) : "memory");
    return r;
}
#define WAITV(n_) do {                                                   \
        asm volatile("s_waitcnt vmcnt(" #n_ ")" ::: "memory");           \
        __builtin_amdgcn_sched_barrier(0);                               \
    } while (0)

__device__ __forceinline__ float wave_reduce(float v) {
#pragma unroll
    for (int off = 32; off; off >>= 1) v += __shfl_xor(v, off, 64);
    return v;
}

// 4096 blocks, 256 threads, 512 pixels/block.  (R11 body, unchanged)
template<bool USE_PART>
__global__ __launch_bounds__(256, 4) void niou_partial(
    const float* __restrict__ pd, const float* __restrict__ gt,
    const int* __restrict__ pmask, const int* __restrict__ gmask,
    float* __restrict__ outp,        /* USE_PART ? part[320][BPI] : ws atomic [320][16] */
    float* __restrict__ accum,       /* USE_PART only */
    unsigned int* __restrict__ ticket)
{
    if (USE_PART && blockIdx.x == 0 && threadIdx.x == 0) {
        *accum = 0.f;                 // stream-ordered before niou_tail64;
        *ticket = 0u;                 // nothing else touches these here
    }

    __shared__ float dnL[512], poL[512], goL[512];   // unpadded: b64 W / b128 R

    const int tid  = threadIdx.x;
    const int b    = blockIdx.x >> 9;
    const int blk  = blockIdx.x & 511;
    const int base = blk * 512;

    // ---- issue 8 rgbo dwordx2 loads (oldest in queue) ----
    const float* pdB = pd + (size_t)b * 4 * HWc + base + 2 * tid;
    const float* gtB = gt + (size_t)b * 4 * HWc + base + 2 * tid;
    float2 pr[4], gr[4];
#pragma unroll
    for (int c = 0; c < 4; ++c) pr[c] = gload_f2(pdB + (size_t)c * HWc);
#pragma unroll
    for (int c = 0; c < 4; ++c) gr[c] = gload_f2(gtB + (size_t)c * HWc);

    // ---- issue 8 mask int4 loads: planes 2g,2g+1, quads q and q+64 ----
    const int g = tid >> 6, q = tid & 63;
    int4 pmv[2][2], gmv[2][2];   // [plane pp][quad qq]
#pragma unroll
    for (int pp = 0; pp < 2; ++pp) {
        const size_t pl = (size_t)(b * Nc + 2 * g + pp) * HWc + base + 4 * q;
#pragma unroll
        for (int qq = 0; qq < 2; ++qq) {
            pmv[pp][qq] = gload_i4(pmask + pl + 256 * qq);
            gmv[pp][qq] = gload_i4(gmask + pl + 256 * qq);
        }
    }

    // ---- rgbo done (8 oldest); 8 mask loads still in flight ----
    WAITV(8);
    {
        const float dx0 = pr[0].x - gr[0].x, dy0 = pr[1].x - gr[1].x, dz0 = pr[2].x - gr[2].x;
        const float dx1 = pr[0].y - gr[0].y, dy1 = pr[1].y - gr[1].y, dz1 = pr[2].y - gr[2].y;
        float2 d2, p2, g2;
        d2.x = sqrtf(dx0*dx0 + dy0*dy0 + dz0*dz0);
        d2.y = sqrtf(dx1*dx1 + dy1*dy1 + dz1*dz1);
        p2.x = rintf(pr[3].x); p2.y = rintf(pr[3].y);
        g2.x = rintf(gr[3].x); g2.y = rintf(gr[3].y);
        *reinterpret_cast<float2*>(&dnL[2 * tid]) = d2;
        *reinterpret_cast<float2*>(&poL[2 * tid]) = p2;
        *reinterpret_cast<float2*>(&goL[2 * tid]) = g2;
    }
    __syncthreads();

    // ---- LDS pixel quantities for this thread's two quads ----
    float4 dnq[2], poq[2], goq[2];
#pragma unroll
    for (int qq = 0; qq < 2; ++qq) {
        const int li = 256 * qq + 4 * q;
        dnq[qq] = *reinterpret_cast<const float4*>(&dnL[li]);
        poq[qq] = *reinterpret_cast<const float4*>(&poL[li]);
        goq[qq] = *reinterpret_cast<const float4*>(&goL[li]);
    }

    // acc[pp]: {sim_sum, inter, gt_sum, s_sum}; count via ballot
    float acc[2][4];
    int   wcnt[2];
#pragma unroll
    for (int pp = 0; pp < 2; ++pp) {
        wcnt[pp] = 0;
#pragma unroll
        for (int k = 0; k < 4; ++k) acc[pp][k] = 0.f;
    }

    // ---- counted drain: pp=0 ready at vmcnt(4), pp=1 at vmcnt(0) ----
#pragma unroll
    for (int pp = 0; pp < 2; ++pp) {
        if (pp == 0) WAITV(4); else WAITV(0);
#pragma unroll
        for (int qq = 0; qq < 2; ++qq) {
            const int pmx[4] = {pmv[pp][qq].x, pmv[pp][qq].y, pmv[pp][qq].z, pmv[pp][qq].w};
            const int gmx[4] = {gmv[pp][qq].x, gmv[pp][qq].y, gmv[pp][qq].z, gmv[pp][qq].w};
            const float dnj[4] = {dnq[qq].x, dnq[qq].y, dnq[qq].z, dnq[qq].w};
            const float poj[4] = {poq[qq].x, poq[qq].y, poq[qq].z, poq[qq].w};
            const float goj[4] = {goq[qq].x, goq[qq].y, goq[qq].z, goq[qq].w};
#pragma unroll
            for (int j = 0; j < 4; ++j) {
                const bool P = pmx[j] != 0;
                const bool G = gmx[j] != 0;
                wcnt[pp] += __popcll(__ballot(P));
                const float s = P ? poj[j] : 0.f;
                acc[pp][0] += P ? dnj[j] : 0.f;
                acc[pp][1] += G ? s      : 0.f;   // inter = (P&&G)?po:0
                acc[pp][2] += G ? goj[j] : 0.f;
                acc[pp][3] += s;                  // xor = s_sum - inter (tail)
            }
        }
    }

    // ---- wave-level reduction; lane0 stores 10 partials (no atomics) ----
    const int lane = tid & 63;
#pragma unroll
    for (int pp = 0; pp < 2; ++pp) {
        const float s0 = wave_reduce(acc[pp][0]);
        const float s1 = wave_reduce(acc[pp][1]);
        const float s2 = wave_reduce(acc[pp][2]);
        const float s3 = wave_reduce(acc[pp][3]);
        if (lane == 0) {
            const int n = 2 * g + pp;
            if (USE_PART) {
                float* dst = outp + (size_t)(b * 40 + n * 5) * BPI + blk;
                dst[0 * BPI] = s0;
                dst[1 * BPI] = (float)wcnt[pp];
                dst[2 * BPI] = s1;
                dst[3 * BPI] = s2;
                dst[4 * BPI] = s3;
            } else {   // fallback: 20KB atomic layout (PAD=16)
                float* wsn = outp + (size_t)(b * 40 + n * 5) * 16;
                atomicAdd(&wsn[0 * 16], s0);
                atomicAdd(&wsn[1 * 16], (float)wcnt[pp]);
                atomicAdd(&wsn[2 * 16], s1);
                atomicAdd(&wsn[3 * 16], s2);
                atomicAdd(&wsn[4 * 16], s3);
            }
        }
    }
}

// 64 blocks x 256 threads: block bn reduces its 5 x BPI partials -> term_bn
// -> atomicAdd(accum); the 64th ticket holder writes out[0] = accum/64.
__global__ __launch_bounds__(256) void niou_tail64(
    const float* __restrict__ part, float* __restrict__ accum,
    unsigned int* __restrict__ ticket, float* __restrict__ out)
{
    const int bn  = blockIdx.x;      // 0..63 == b*8+n
    const int tid = threadIdx.x;

    float loc[5];
#pragma unroll
    for (int s = 0; s < 5; ++s) {
        const float* row = part + ((size_t)bn * 5 + s) * BPI;
        loc[s] = wave_reduce(row[tid] + row[tid + 256]);
    }

    __shared__ float red[4][5];
    if ((tid & 63) == 0) {
#pragma unroll
        for (int s = 0; s < 5; ++s) red[tid >> 6][s] = loc[s];
    }
    __syncthreads();

    if (tid == 0) {
        const float sim   = red[0][0] + red[1][0] + red[2][0] + red[3][0];
        const float cnt   = red[0][1] + red[1][1] + red[2][1] + red[3][1];
        const float inter = red[0][2] + red[1][2] + red[2][2] + red[3][2];
        const float gts   = red[0][3] + red[1][3] + red[2][3] + red[3][3];
        const float ssum  = red[0][4] + red[1][4] + red[2][4] + red[3][4];
        const float xo    = ssum - inter;            // pd_xor_sum
        const float punish = sim / (cnt + EPSc);
        const float iou    = inter / (gts + xo + EPSc);
        atomicAdd(accum, 1.0f - iou + punish);
        __threadfence();                              // accum add before ticket
        const unsigned int old = atomicAdd(ticket, 1u);
        if (old == 63u) {                             // all 64 accum adds done
            const float tot = __hip_atomic_load(accum, __ATOMIC_RELAXED,
                                                __HIP_MEMORY_SCOPE_AGENT);
            out[0] = tot * (1.0f / 64.0f);
        }
    }
}

__global__ __launch_bounds__(64) void niou_final_fb(
    const float* __restrict__ w0, float* __restrict__ out)
{
    const int t = threadIdx.x;   // 0..63 == b*8+n
    const float* w = w0 + (size_t)t * 5 * 16;
    const float sim   = w[0 * 16];
    const float cnt   = w[1 * 16];
    const float inter = w[2 * 16];
    const float gts   = w[3 * 16];
    const float ssum  = w[4 * 16];
    const float xo    = ssum - inter;
    const float punish = sim / (cnt + EPSc);
    const float iou    = inter / (gts + xo + EPSc);
    float term = 1.0f - iou + punish;
#pragma unroll
    for (int off = 32; off; off >>= 1) term += __shfl_xor(term, off, 64);
    if (t == 0) out[0] = term * (1.0f / 64.0f);
}

extern "C" void kernel_launch(void* const* d_in, const int* in_sizes, int n_in,
                              void* d_out, int out_size, void* d_ws, size_t ws_size,
                              hipStream_t stream) {
    const float* pd_rgbo = (const float*)d_in[0];
    const float* gt_rgbo = (const float*)d_in[1];
    const int*   pd_mask = (const int*)d_in[2];
    const int*   gt_mask = (const int*)d_in[3];
    float* out = (float*)d_out;
    float* ws  = (float*)d_ws;

    const size_t need = (PARTN + 2) * sizeof(float);
    if (ws_size >= need) {
        float* part = ws;
        float* accum = ws + PARTN;
        unsigned int* ticket = (unsigned int*)(ws + PARTN + 1);
        niou_partial<true><<<Bc * BPI, 256, 0, stream>>>(pd_rgbo, gt_rgbo,
                                                         pd_mask, gt_mask,
                                                         part, accum, ticket);
        niou_tail64<<<64, 256, 0, stream>>>(part, accum, ticket, out);
    } else {
        hipMemsetAsync(ws, 0, 320 * 16 * sizeof(float), stream);
        niou_partial<false><<<Bc * BPI, 256, 0, stream>>>(pd_rgbo, gt_rgbo,
                                                          pd_mask, gt_mask,
                                                          ws, nullptr, nullptr);
        niou_final_fb<<<1, 64, 0, stream>>>(ws, out);
    }
}